// Round 15
// baseline (699.463 us; speedup 1.0000x reference)
//
#include <hip/hip_runtime.h>
#include <cstdint>

#define SSn 5440
#define TTn 21760
#define TD ((size_t)TTn*256)
#define NL 6

typedef short bf16x8 __attribute__((ext_vector_type(8)));
typedef float f32x4 __attribute__((ext_vector_type(4)));
typedef float f32x2 __attribute__((ext_vector_type(2)));
typedef unsigned short u16x4 __attribute__((ext_vector_type(4)));
typedef unsigned short ushort_t;

__device__ __forceinline__ ushort_t f2b(float f) {
  uint32_t x = __float_as_uint(f);
  uint32_t r = x + 0x7FFFu + ((x >> 16) & 1u);
  return (ushort_t)(r >> 16);
}
__device__ __forceinline__ float b2f(ushort_t u) {
  return __uint_as_float((uint32_t)u << 16);
}

// ---------------------------------------------------------------------------
// Preprocess: tiled 64x64 LDS transpose. 340 tiles/batch x 4 = 1360 blocks.
// bf16 spine: no f32 cur output.
__global__ __launch_bounds__(256) void prep_kernel(
    const float* __restrict__ s0, const float* __restrict__ p0,
    const float* __restrict__ s1, const float* __restrict__ p1,
    const float* __restrict__ s2, const float* __restrict__ p2,
    const float* __restrict__ s3, const float* __restrict__ p3,
    const float* __restrict__ lev,
    ushort_t* __restrict__ cur_b,
    ushort_t* __restrict__ pos_b, ushort_t* __restrict__ q_b)
{
  __shared__ float ts[64][65];
  __shared__ float tp[64][65];
  int bx = blockIdx.x;
  int b = bx / 340, r = bx % 340;
  const float *sp, *pp; int l, HW, start, dt, ptile;
  if (r < 256)      { l=0; HW=4096; start=0;    sp=s0; pp=p0; dt=r>>6;       ptile=r&63; }
  else if (r < 320) { l=1; HW=1024; start=4096; sp=s1; pp=p1; dt=(r-256)>>4; ptile=(r-256)&15; }
  else if (r < 336) { l=2; HW=256;  start=5120; sp=s2; pp=p2; dt=(r-320)>>2; ptile=(r-320)&3; }
  else              { l=3; HW=64;   start=5376; sp=s3; pp=p3; dt=r-336;      ptile=0; }
  int d0 = dt * 64, pp0 = ptile * 64;
  int t = threadIdx.x;
  int rr = t >> 2, c4 = (t & 3) * 16;
  size_t ibase = ((size_t)b * 256 + d0 + rr) * HW + pp0;
  #pragma unroll
  for (int i = 0; i < 4; ++i) {
    f32x4 v = *(const f32x4*)(sp + ibase + c4 + i * 4);
    f32x4 w = *(const f32x4*)(pp + ibase + c4 + i * 4);
    #pragma unroll
    for (int j = 0; j < 4; ++j) { ts[c4 + i*4 + j][rr] = v[j]; tp[c4 + i*4 + j][rr] = w[j]; }
  }
  __syncthreads();
  int token = start + pp0 + rr;
  size_t obase = ((size_t)b * SSn + token) * 256 + d0;
  #pragma unroll
  for (int i = 0; i < 4; ++i) {
    u16x4 cb, pb, qb;
    #pragma unroll
    for (int j = 0; j < 4; ++j) {
      float c = ts[rr][c4 + i*4 + j];
      float p = tp[rr][c4 + i*4 + j] + lev[l * 256 + d0 + c4 + i*4 + j];
      cb[j] = f2b(c); pb[j] = f2b(p); qb[j] = f2b(c + p);
    }
    *(u16x4*)(cur_b + obase + c4 + i*4) = cb;
    *(u16x4*)(pos_b + obase + c4 + i*4) = pb;
    *(u16x4*)(q_b + obase + c4 + i*4) = qb;
  }
}

// ---------------------------------------------------------------------------
// Batched weight transpose+convert. Column-permuted placement: original
// output-column o stored at virtual row V(o)=((o&3)<<4)|(o>>2) within its
// 64-col group -> packed u16x4 epilogue stores.
__global__ __launch_bounds__(256) void wprep_kernel(
    const float* __restrict__ W_so, const float* __restrict__ W_aw,
    const float* __restrict__ W_v,  const float* __restrict__ W_o,
    const float* __restrict__ W_f1, const float* __restrict__ W_f2,
    ushort_t* __restrict__ wt)
{
  __shared__ float tile[64][65];
  int bx = blockIdx.x;
  int layer = bx / 184, r = bx % 184;
  int type, ti;
  if (r < 16)       { type = 0; ti = r; }
  else if (r < 24)  { type = 1; ti = r - 16; }
  else if (r < 40)  { type = 2; ti = r - 24; }
  else if (r < 56)  { type = 3; ti = r - 40; }
  else if (r < 120) { type = 4; ti = r - 56; }
  else              { type = 5; ti = r - 120; }
  const float* src;
  int K, N, dof;
  switch (type) {
    case 0: src = W_so + (size_t)layer * 65536;  K = 256;  N = 256;  dof = 0;      break;
    case 1: src = W_aw + (size_t)layer * 32768;  K = 256;  N = 128;  dof = 65536;  break;
    case 2: src = W_v  + (size_t)layer * 65536;  K = 256;  N = 256;  dof = 98304;  break;
    case 3: src = W_o  + (size_t)layer * 65536;  K = 256;  N = 256;  dof = 163840; break;
    case 4: src = W_f1 + (size_t)layer * 262144; K = 256;  N = 1024; dof = 229376; break;
    default:src = W_f2 + (size_t)layer * 262144; K = 1024; N = 256;  dof = 491520; break;
  }
  int Kt = K >> 6;
  int k0 = (ti % Kt) * 64, n0 = (ti / Kt) * 64;
  ushort_t* dst = wt + (size_t)layer * 753664 + dof;
  int t = threadIdx.x;
  int rr = t >> 2, c4 = (t & 3) * 16;
  #pragma unroll
  for (int i = 0; i < 4; ++i) {
    f32x4 v = *(const f32x4*)(src + (size_t)(k0 + rr) * N + n0 + c4 + i * 4);
    tile[c4 + i*4 + 0][rr] = v[0];
    tile[c4 + i*4 + 1][rr] = v[1];
    tile[c4 + i*4 + 2][rr] = v[2];
    tile[c4 + i*4 + 3][rr] = v[3];
  }
  __syncthreads();
  int vrow = ((rr & 3) << 4) | (rr >> 2);   // V(rr): epilogue-pack permutation
  #pragma unroll
  for (int i = 0; i < 4; ++i) {
    u16x4 o;
    #pragma unroll
    for (int j = 0; j < 4; ++j) o[j] = f2b(tile[rr][c4 + i*4 + j]);
    *(u16x4*)(dst + (size_t)(n0 + vrow) * K + k0 + c4 + i * 4) = o;
  }
}

__global__ void bias_fuse(const float* __restrict__ bso,
                          const float* __restrict__ baw,
                          float* __restrict__ bsa)
{
  int l = blockIdx.x, t = threadIdx.x;
  bsa[l * 384 + t] = (t < 256) ? bso[l * 256 + t] : baw[l * 128 + t - 256];
}

// ---------------------------------------------------------------------------
// 8-wave 256x128 MFMA GEMM body (BK=64, 512 threads, swizzled LDS).
__device__ __forceinline__ void gemm_body8(
    ushort_t* As, ushort_t* Bs,
    const ushort_t* __restrict__ A, const ushort_t* __restrict__ Bt,
    const float* __restrict__ bias, ushort_t* __restrict__ Cb,
    int N, int n0, int m0, int K, int relu)
{
  int t = threadIdx.x;
  int l = t & 63, w = t >> 6;
  int wr = w >> 1, wc = w & 1;
  int lq = l >> 4, l15 = l & 15, r7 = l & 7;
  f32x4 acc[4][4] = {};

  for (int k0 = 0; k0 < K; k0 += 64) {
    #pragma unroll
    for (int i = 0; i < 4; ++i) {
      int c = i * 512 + t;
      int row = c >> 3;
      int sc = (c & 7) ^ (row & 7);
      __builtin_amdgcn_global_load_lds(
          (const uint32_t*)(A + (size_t)(m0 + row) * K + k0 + sc * 8),
          (uint32_t*)((char*)As + c * 16), 16, 0, 0);
    }
    #pragma unroll
    for (int i = 0; i < 2; ++i) {
      int c = i * 512 + t;
      int row = c >> 3;
      int sc = (c & 7) ^ (row & 7);
      __builtin_amdgcn_global_load_lds(
          (const uint32_t*)(Bt + (size_t)(n0 + row) * K + k0 + sc * 8),
          (uint32_t*)((char*)Bs + c * 16), 16, 0, 0);
    }
    __syncthreads();
    #pragma unroll
    for (int ks = 0; ks < 2; ++ks) {
      bf16x8 af[4], bfr[4];
      int chs = ((ks << 2) + lq) ^ r7;
      #pragma unroll
      for (int mt = 0; mt < 4; ++mt)
        af[mt] = *(const bf16x8*)((const char*)As +
                   (wr * 64 + mt * 16 + l15) * 128 + (chs << 4));
      #pragma unroll
      for (int nt = 0; nt < 4; ++nt)
        bfr[nt] = *(const bf16x8*)((const char*)Bs +
                   (wc * 64 + nt * 16 + l15) * 128 + (chs << 4));
      #pragma unroll
      for (int mt = 0; mt < 4; ++mt)
        #pragma unroll
        for (int nt = 0; nt < 4; ++nt)
          acc[mt][nt] = __builtin_amdgcn_mfma_f32_16x16x32_bf16(
              af[mt], bfr[nt], acc[mt][nt], 0, 0, 0);
    }
    __syncthreads();
  }

  int crow0 = m0 + wr * 64;
  int cb = n0 + wc * 64 + l15 * 4;
  f32x4 bv4 = *(const f32x4*)(bias + cb);
  #pragma unroll
  for (int mt = 0; mt < 4; ++mt) {
    #pragma unroll
    for (int r = 0; r < 4; ++r) {
      int rowg = crow0 + mt * 16 + lq * 4 + r;
      u16x4 o;
      #pragma unroll
      for (int nt = 0; nt < 4; ++nt) {
        float v = acc[mt][nt][r] + bv4[nt];
        if (relu) v = fmaxf(v, 0.f);
        o[nt] = f2b(v);
      }
      *(u16x4*)(Cb + (size_t)rowg * N + cb) = o;
    }
  }
}

// FFN1 GEMM (relu), 256x128 tiles
__global__ __launch_bounds__(512) void gemm_mfma(
    const ushort_t* __restrict__ A, const ushort_t* __restrict__ Bt,
    const float* __restrict__ bias, ushort_t* __restrict__ Cb,
    int N, int K, int relu)
{
  __shared__ alignas(16) ushort_t As[16384];
  __shared__ alignas(16) ushort_t Bs[8192];
  gemm_body8(As, Bs, A, Bt, bias, Cb, N, blockIdx.y * 128, blockIdx.x * 256, K, relu);
}

// Merged sa(q@Wsa, N=384) + val(cur@Wv, N=256): grid (85, 5), 256-row tiles
__global__ __launch_bounds__(512) void gemm_dual(
    const ushort_t* __restrict__ A0, const ushort_t* __restrict__ Bt0,
    const float* __restrict__ bias0, ushort_t* __restrict__ C0,
    const ushort_t* __restrict__ A1, const ushort_t* __restrict__ Bt1,
    const float* __restrict__ bias1, ushort_t* __restrict__ C1,
    int K)
{
  __shared__ alignas(16) ushort_t As[16384];
  __shared__ alignas(16) ushort_t Bs[8192];
  int gy = blockIdx.y;
  if (gy < 3)
    gemm_body8(As, Bs, A0, Bt0, bias0, C0, 384, gy * 128, blockIdx.x * 256, K, 0);
  else
    gemm_body8(As, Bs, A1, Bt1, bias1, C1, 256, (gy - 3) * 128, blockIdx.x * 256, K, 0);
}

// ---------------------------------------------------------------------------
// Fused GEMM (N=256) + residual(bf16) + LayerNorm. Tile 64x256, 8 waves.
// Of (f32) written only when non-null (final layer).
__global__ __launch_bounds__(512) void gemm_ln(
    const ushort_t* __restrict__ A, const ushort_t* __restrict__ Bt,
    const float* __restrict__ bias, const ushort_t* __restrict__ resb,
    const float* __restrict__ g, const float* __restrict__ be,
    float* __restrict__ Of, ushort_t* __restrict__ Ob,
    ushort_t* __restrict__ Oq, const ushort_t* __restrict__ posb,
    int K)
{
  __shared__ alignas(16) ushort_t As[64 * 64];
  __shared__ alignas(16) ushort_t Bs[256 * 64];
  __shared__ float psum[64][4];
  __shared__ float psum2[64][4];
  __shared__ float2 mstd[64];
  int t = threadIdx.x;
  int l = t & 63, w = t >> 6;
  int wr = w >> 2, wc = w & 3;
  int m0 = blockIdx.x * 64;
  int lq = l >> 4, l15 = l & 15, r7 = l & 7;
  f32x4 acc[2][4] = {};

  for (int k0 = 0; k0 < K; k0 += 64) {
    {
      int c = t;
      int row = c >> 3;
      int sc = (c & 7) ^ (row & 7);
      __builtin_amdgcn_global_load_lds(
          (const uint32_t*)(A + (size_t)(m0 + row) * K + k0 + sc * 8),
          (uint32_t*)((char*)As + c * 16), 16, 0, 0);
    }
    #pragma unroll
    for (int i = 0; i < 4; ++i) {
      int c = i * 512 + t;
      int row = c >> 3;
      int sc = (c & 7) ^ (row & 7);
      __builtin_amdgcn_global_load_lds(
          (const uint32_t*)(Bt + (size_t)row * K + k0 + sc * 8),
          (uint32_t*)((char*)Bs + c * 16), 16, 0, 0);
    }
    __syncthreads();
    #pragma unroll
    for (int ks = 0; ks < 2; ++ks) {
      bf16x8 af[2], bfr[4];
      int chs = ((ks << 2) + lq) ^ r7;
      #pragma unroll
      for (int mt = 0; mt < 2; ++mt)
        af[mt] = *(const bf16x8*)((const char*)As +
                   (wr * 32 + mt * 16 + l15) * 128 + (chs << 4));
      #pragma unroll
      for (int nt = 0; nt < 4; ++nt)
        bfr[nt] = *(const bf16x8*)((const char*)Bs +
                   (wc * 64 + nt * 16 + l15) * 128 + (chs << 4));
      #pragma unroll
      for (int mt = 0; mt < 2; ++mt)
        #pragma unroll
        for (int nt = 0; nt < 4; ++nt)
          acc[mt][nt] = __builtin_amdgcn_mfma_f32_16x16x32_bf16(
              af[mt], bfr[nt], acc[mt][nt], 0, 0, 0);
    }
    __syncthreads();
  }

  int cb = wc * 64 + l15 * 4;
  f32x4 g4 = *(const f32x4*)(g + cb);
  f32x4 be4 = *(const f32x4*)(be + cb);
  f32x4 b4 = *(const f32x4*)(bias + cb);
  #pragma unroll
  for (int mt = 0; mt < 2; ++mt) {
    #pragma unroll
    for (int r = 0; r < 4; ++r) {
      int rowg = m0 + wr * 32 + mt * 16 + lq * 4 + r;
      u16x4 r4 = *(const u16x4*)(resb + (size_t)rowg * 256 + cb);
      #pragma unroll
      for (int nt = 0; nt < 4; ++nt)
        acc[mt][nt][r] += b4[nt] + b2f(r4[nt]);
    }
  }
  #pragma unroll
  for (int mt = 0; mt < 2; ++mt) {
    #pragma unroll
    for (int r = 0; r < 4; ++r) {
      float s = 0.f, s2 = 0.f;
      #pragma unroll
      for (int nt = 0; nt < 4; ++nt) {
        float v = acc[mt][nt][r];
        s += v; s2 += v * v;
      }
      #pragma unroll
      for (int off = 1; off < 16; off <<= 1) {
        s  += __shfl_xor(s, off);
        s2 += __shfl_xor(s2, off);
      }
      if (l15 == 0) {
        int rloc = wr * 32 + mt * 16 + lq * 4 + r;
        psum[rloc][wc] = s;
        psum2[rloc][wc] = s2;
      }
    }
  }
  __syncthreads();
  if (t < 64) {
    f32x4 a = *(const f32x4*)psum[t];
    f32x4 b = *(const f32x4*)psum2[t];
    float s = a[0] + a[1] + a[2] + a[3];
    float s2 = b[0] + b[1] + b[2] + b[3];
    float mean = s * (1.f / 256.f);
    float var = s2 * (1.f / 256.f) - mean * mean;
    mstd[t] = make_float2(mean, rsqrtf(var + 1e-5f));
  }
  __syncthreads();
  #pragma unroll
  for (int mt = 0; mt < 2; ++mt) {
    #pragma unroll
    for (int r = 0; r < 4; ++r) {
      int rloc = wr * 32 + mt * 16 + lq * 4 + r;
      int rowg = m0 + rloc;
      float2 ms = mstd[rloc];
      size_t o = (size_t)rowg * 256 + cb;
      f32x4 y4; u16x4 yb;
      #pragma unroll
      for (int nt = 0; nt < 4; ++nt) {
        float y = (acc[mt][nt][r] - ms.x) * ms.y * g4[nt] + be4[nt];
        y4[nt] = y; yb[nt] = f2b(y);
      }
      if (Of) *(f32x4*)(Of + o) = y4;
      *(u16x4*)(Ob + o) = yb;
      if (Oq) {
        u16x4 p4 = *(const u16x4*)(posb + o);
        u16x4 q4;
        #pragma unroll
        for (int nt = 0; nt < 4; ++nt) q4[nt] = f2b(y4[nt] + b2f(p4[nt]));
        *(u16x4*)(Oq + o) = q4;
      }
    }
  }
}

// ---------------------------------------------------------------------------
// Deformable sampling v10: 4 tokens/block, 128 threads (finer scheduling
// granularity -> higher occupancy), 32 thr/token, XCD swizzle (5440 = 8*680).
__global__ __launch_bounds__(128, 8) void sample_kernel(
    const ushort_t* __restrict__ val, const ushort_t* __restrict__ sa,
    ushort_t* __restrict__ att)
{
  __shared__ uint4 rec[4][136];
  int tid = threadIdx.x;
  int bid = blockIdx.x;
  int t0 = ((bid & 7) * 680 + (bid >> 3)) * 4;

  #pragma unroll
  for (int it = 0; it < 4; ++it) {
    int idx = it * 128 + tid;        // 0..511 over 4 tokens x 128 pts
    int tl = idx >> 7;
    int pt = idx & 127;
    int t = t0 + tl;
    int b = t / SSn, s = t % SSn;
    int lvl = (pt >> 2) & 3;
    int st, Wt;
    if (s < 4096)      { st = 0;    Wt = 64; }
    else if (s < 5120) { st = 4096; Wt = 32; }
    else if (s < 5376) { st = 5120; Wt = 16; }
    else               { st = 5376; Wt = 8;  }
    int p = s - st;
    int iy = p / Wt, ix = p % Wt;
    float refx = (ix + 0.5f) / Wt;
    float refy = (iy + 0.5f) / Wt;

    float logit = b2f(sa[(size_t)t * 384 + 256 + pt]);
    float m = logit;
    #pragma unroll
    for (int off = 1; off < 16; off <<= 1) m = fmaxf(m, __shfl_xor(m, off));
    float e = __expf(logit - m);
    float sum = e;
    #pragma unroll
    for (int off = 1; off < 16; off <<= 1) sum += __shfl_xor(sum, off);
    float wa = e / sum;

    const int LWt[4] = {64, 32, 16, 8};
    const int LST[4] = {0, 4096, 5120, 5376};
    int Wl = LWt[lvl], Hl = Wl, stl = LST[lvl];

    uint32_t oxy = *(const uint32_t*)(sa + (size_t)t * 384 + pt * 2);
    float ox = __uint_as_float(oxy << 16);
    float oy = __uint_as_float(oxy & 0xFFFF0000u);
    float x = refx * Wl + ox - 0.5f;
    float y = refy * Hl + oy - 0.5f;
    float x0f = floorf(x), y0f = floorf(y);
    int x0 = (int)x0f, y0 = (int)y0f;
    float wx1 = x - x0f, wy1 = y - y0f;
    int vbase = b * SSn + stl;
    uint32_t ipk[4]; uint32_t wpk[4];
    #pragma unroll
    for (int c = 0; c < 4; ++c) {
      int dx = c & 1, dy = c >> 1;
      int xi = x0 + dx, yi = y0 + dy;
      float wgt = (dx ? wx1 : 1.f - wx1) * (dy ? wy1 : 1.f - wy1);
      bool valid = (xi >= 0) & (xi < Wl) & (yi >= 0) & (yi < Hl);
      int xc = min(max(xi, 0), Wl - 1), yc = min(max(yi, 0), Hl - 1);
      ipk[c] = (uint32_t)(vbase + yc * Wl + xc);
      wpk[c] = valid ? (uint32_t)f2b(wgt * wa) : 0u;
    }
    uint4 r;
    r.x = ipk[0] | (ipk[1] << 16);
    r.y = ipk[2] | (ipk[3] << 16);
    r.z = wpk[0] | (wpk[1] << 16);
    r.w = wpk[2] | (wpk[3] << 16);
    rec[tl][pt + (pt >> 4)] = r;
  }
  __syncthreads();

  int tl = tid >> 5, v = tid & 31;
  int t = t0 + tl;
  int h = v >> 2, j = v & 3;
  int c0 = h * 32 + j * 8;
  uint32_t cb2 = (uint32_t)(c0 * 2);
  const char* vb = (const char*)val;
  f32x2 acA[4] = {}, acB[4] = {};
  #pragma unroll
  for (int k = 0; k < 16; k += 2) {
    uint4 rA = rec[tl][h * 17 + k];
    uint4 rB = rec[tl][h * 17 + k + 1];
    uint32_t oA0 = ((rA.x & 0xFFFFu) << 9) + cb2;
    uint32_t oA1 = ((rA.x >> 16)     << 9) + cb2;
    uint32_t oA2 = ((rA.y & 0xFFFFu) << 9) + cb2;
    uint32_t oA3 = ((rA.y >> 16)     << 9) + cb2;
    uint32_t oB0 = ((rB.x & 0xFFFFu) << 9) + cb2;
    uint32_t oB1 = ((rB.x >> 16)     << 9) + cb2;
    uint32_t oB2 = ((rB.y & 0xFFFFu) << 9) + cb2;
    uint32_t oB3 = ((rB.y >> 16)     << 9) + cb2;
    uint4 uA0 = *(const uint4*)(vb + oA0);
    uint4 uA1 = *(const uint4*)(vb + oA1);
    uint4 uA2 = *(const uint4*)(vb + oA2);
    uint4 uA3 = *(const uint4*)(vb + oA3);
    uint4 uB0 = *(const uint4*)(vb + oB0);
    uint4 uB1 = *(const uint4*)(vb + oB1);
    uint4 uB2 = *(const uint4*)(vb + oB2);
    uint4 uB3 = *(const uint4*)(vb + oB3);
    float wA[4] = { __uint_as_float(rA.z << 16),
                    __uint_as_float(rA.z & 0xFFFF0000u),
                    __uint_as_float(rA.w << 16),
                    __uint_as_float(rA.w & 0xFFFF0000u) };
    float wB[4] = { __uint_as_float(rB.z << 16),
                    __uint_as_float(rB.z & 0xFFFF0000u),
                    __uint_as_float(rB.w << 16),
                    __uint_as_float(rB.w & 0xFFFF0000u) };
    const uint4* uvA[4] = { &uA0, &uA1, &uA2, &uA3 };
    const uint4* uvB[4] = { &uB0, &uB1, &uB2, &uB3 };
    #pragma unroll
    for (int c = 0; c < 4; ++c) {
      uint4 uv = *uvA[c];
      f32x2 w2 = {wA[c], wA[c]};
      f32x2 p0 = {__uint_as_float(uv.x << 16), __uint_as_float(uv.x & 0xFFFF0000u)};
      f32x2 p1 = {__uint_as_float(uv.y << 16), __uint_as_float(uv.y & 0xFFFF0000u)};
      f32x2 p2 = {__uint_as_float(uv.z << 16), __uint_as_float(uv.z & 0xFFFF0000u)};
      f32x2 p3 = {__uint_as_float(uv.w << 16), __uint_as_float(uv.w & 0xFFFF0000u)};
      acA[0] += w2 * p0; acA[1] += w2 * p1; acA[2] += w2 * p2; acA[3] += w2 * p3;
    }
    #pragma unroll
    for (int c = 0; c < 4; ++c) {
      uint4 uv = *uvB[c];
      f32x2 w2 = {wB[c], wB[c]};
      f32x2 p0 = {__uint_as_float(uv.x << 16), __uint_as_float(uv.x & 0xFFFF0000u)};
      f32x2 p1 = {__uint_as_float(uv.y << 16), __uint_as_float(uv.y & 0xFFFF0000u)};
      f32x2 p2 = {__uint_as_float(uv.z << 16), __uint_as_float(uv.z & 0xFFFF0000u)};
      f32x2 p3 = {__uint_as_float(uv.w << 16), __uint_as_float(uv.w & 0xFFFF0000u)};
      acB[0] += w2 * p0; acB[1] += w2 * p1; acB[2] += w2 * p2; acB[3] += w2 * p3;
    }
  }
  #pragma unroll
  for (int i = 0; i < 4; ++i) acA[i] += acB[i];
  uint4 pk;
  pk.x = (uint32_t)f2b(acA[0][0]) | ((uint32_t)f2b(acA[0][1]) << 16);
  pk.y = (uint32_t)f2b(acA[1][0]) | ((uint32_t)f2b(acA[1][1]) << 16);
  pk.z = (uint32_t)f2b(acA[2][0]) | ((uint32_t)f2b(acA[2][1]) << 16);
  pk.w = (uint32_t)f2b(acA[3][0]) | ((uint32_t)f2b(acA[3][1]) << 16);
  *(uint4*)(att + (size_t)t * 256 + c0) = pk;
}

// ---------------------------------------------------------------------------
__global__ void tail_kernel(float* __restrict__ o) {
  const float v[12] = {64.f, 64.f, 32.f, 32.f, 16.f, 16.f, 8.f, 8.f,
                       0.f, 4096.f, 5120.f, 5376.f};
  int i = threadIdx.x;
  if (i < 12) o[i] = v[i];
}

// ---------------------------------------------------------------------------
extern "C" void kernel_launch(void* const* d_in, const int* in_sizes, int n_in,
                              void* d_out, int out_size, void* d_ws, size_t ws_size,
                              hipStream_t stream)
{
  const float* s0  = (const float*)d_in[0];
  const float* p0  = (const float*)d_in[1];
  const float* s1  = (const float*)d_in[2];
  const float* p1  = (const float*)d_in[3];
  const float* s2  = (const float*)d_in[4];
  const float* p2  = (const float*)d_in[5];
  const float* s3  = (const float*)d_in[6];
  const float* p3  = (const float*)d_in[7];
  const float* lev = (const float*)d_in[8];
  const float* W_so = (const float*)d_in[9];
  const float* b_so = (const float*)d_in[10];
  const float* W_aw = (const float*)d_in[11];
  const float* b_aw = (const float*)d_in[12];
  const float* W_v  = (const float*)d_in[13];
  const float* b_v  = (const float*)d_in[14];
  const float* W_o  = (const float*)d_in[15];
  const float* b_o  = (const float*)d_in[16];
  const float* g1   = (const float*)d_in[17];
  const float* be1  = (const float*)d_in[18];
  const float* W_f1 = (const float*)d_in[19];
  const float* b_f1 = (const float*)d_in[20];
  const float* W_f2 = (const float*)d_in[21];
  const float* b_f2 = (const float*)d_in[22];
  const float* g2   = (const float*)d_in[23];
  const float* be2  = (const float*)d_in[24];

  float* out = (float*)d_out;
  float* ws  = (float*)d_ws;

  // workspace layout (f32 units)
  ushort_t* pos_b = (ushort_t*)ws;                          // 0.5 TD
  ushort_t* q_b   = (ushort_t*)(ws + TD / 2);               // 0.5 TD (q / att)
  ushort_t* cur_b = (ushort_t*)(ws + TD);                   // 0.5 TD
  ushort_t* x_b   = (ushort_t*)(ws + TD + TD / 2);          // 0.5 TD
  // H region: phase1 sa_b (0.75 TD) + val_b (0.5 TD); phase3 h_b (2 TD)
  ushort_t* sa_b  = (ushort_t*)(ws + 2 * TD);
  ushort_t* val_b = (ushort_t*)(ws + 2 * TD + 3 * (TD / 4));
  ushort_t* h_b   = (ushort_t*)(ws + 2 * TD);
  ushort_t* wt    = (ushort_t*)(ws + 4 * TD);               // 4,521,984 bf16
  float*    bsa   = ws + 4 * TD + 2260992;                  // 6*384 f32

  const size_t LW = 753664;  // per-layer transposed-weight stride (bf16)

  wprep_kernel<<<1104, 256, 0, stream>>>(W_so, W_aw, W_v, W_o, W_f1, W_f2, wt);
  bias_fuse<<<NL, 384, 0, stream>>>(b_so, b_aw, bsa);
  prep_kernel<<<1360, 256, 0, stream>>>(s0, p0, s1, p1, s2, p2, s3, p3, lev,
                                        cur_b, pos_b, q_b);

  for (int i = 0; i < NL; ++i) {
    ushort_t* wl = wt + (size_t)i * LW;
    const float* bv  = b_v  + (size_t)i * 256;
    const float* bo  = b_o  + (size_t)i * 256;
    const float* bf1 = b_f1 + (size_t)i * 1024;
    const float* bf2 = b_f2 + (size_t)i * 256;

    // merged: sa = q@Wsa (N=384) and val = cur@Wv (N=256), 256-row tiles
    gemm_dual<<<dim3(85, 5), 512, 0, stream>>>(q_b, wl + 0, bsa + i * 384, sa_b,
                                               cur_b, wl + 98304, bv, val_b, 256);
    // deformable sampling -> att (bf16, overwrites q_b)
    sample_kernel<<<TTn / 4, 128, 0, stream>>>(val_b, sa_b, q_b);
    // Wo projection + residual(cur_b) + LN1 -> x_b (bf16 only)
    gemm_ln<<<340, 512, 0, stream>>>(q_b, wl + 163840, bo, cur_b,
                                     g1 + i * 256, be1 + i * 256,
                                     nullptr, x_b, nullptr, nullptr, 256);
    // FFN1 (relu) -> h_b, 256x128 tiles
    gemm_mfma<<<dim3(85, 8), 512, 0, stream>>>(x_b, wl + 229376, bf1,
                                               h_b, 1024, 256, 1);
    // FFN2 + residual(x_b) + LN2 -> cur_b, q_b(next = y+pos); f32 out on last
    gemm_ln<<<340, 512, 0, stream>>>(h_b, wl + 491520, bf2, x_b,
                                     g2 + i * 256, be2 + i * 256,
                                     (i == NL - 1) ? out : nullptr,
                                     cur_b, q_b, pos_b, 1024);
  }

  tail_kernel<<<1, 16, 0, stream>>>(out + TD);
}

// Round 16
// 693.069 us; speedup vs baseline: 1.0092x; 1.0092x over previous
//
#include <hip/hip_runtime.h>
#include <cstdint>

#define SSn 5440
#define TTn 21760
#define TD ((size_t)TTn*256)
#define NL 6

typedef short bf16x8 __attribute__((ext_vector_type(8)));
typedef float f32x4 __attribute__((ext_vector_type(4)));
typedef float f32x2 __attribute__((ext_vector_type(2)));
typedef unsigned short u16x4 __attribute__((ext_vector_type(4)));
typedef unsigned short ushort_t;

__device__ __forceinline__ ushort_t f2b(float f) {
  uint32_t x = __float_as_uint(f);
  uint32_t r = x + 0x7FFFu + ((x >> 16) & 1u);
  return (ushort_t)(r >> 16);
}
__device__ __forceinline__ float b2f(ushort_t u) {
  return __uint_as_float((uint32_t)u << 16);
}

// ---------------------------------------------------------------------------
// Preprocess: tiled 64x64 LDS transpose. 340 tiles/batch x 4 = 1360 blocks.
// bf16 spine: no f32 cur output.
__global__ __launch_bounds__(256) void prep_kernel(
    const float* __restrict__ s0, const float* __restrict__ p0,
    const float* __restrict__ s1, const float* __restrict__ p1,
    const float* __restrict__ s2, const float* __restrict__ p2,
    const float* __restrict__ s3, const float* __restrict__ p3,
    const float* __restrict__ lev,
    ushort_t* __restrict__ cur_b,
    ushort_t* __restrict__ pos_b, ushort_t* __restrict__ q_b)
{
  __shared__ float ts[64][65];
  __shared__ float tp[64][65];
  int bx = blockIdx.x;
  int b = bx / 340, r = bx % 340;
  const float *sp, *pp; int l, HW, start, dt, ptile;
  if (r < 256)      { l=0; HW=4096; start=0;    sp=s0; pp=p0; dt=r>>6;       ptile=r&63; }
  else if (r < 320) { l=1; HW=1024; start=4096; sp=s1; pp=p1; dt=(r-256)>>4; ptile=(r-256)&15; }
  else if (r < 336) { l=2; HW=256;  start=5120; sp=s2; pp=p2; dt=(r-320)>>2; ptile=(r-320)&3; }
  else              { l=3; HW=64;   start=5376; sp=s3; pp=p3; dt=r-336;      ptile=0; }
  int d0 = dt * 64, pp0 = ptile * 64;
  int t = threadIdx.x;
  int rr = t >> 2, c4 = (t & 3) * 16;
  size_t ibase = ((size_t)b * 256 + d0 + rr) * HW + pp0;
  #pragma unroll
  for (int i = 0; i < 4; ++i) {
    f32x4 v = *(const f32x4*)(sp + ibase + c4 + i * 4);
    f32x4 w = *(const f32x4*)(pp + ibase + c4 + i * 4);
    #pragma unroll
    for (int j = 0; j < 4; ++j) { ts[c4 + i*4 + j][rr] = v[j]; tp[c4 + i*4 + j][rr] = w[j]; }
  }
  __syncthreads();
  int token = start + pp0 + rr;
  size_t obase = ((size_t)b * SSn + token) * 256 + d0;
  #pragma unroll
  for (int i = 0; i < 4; ++i) {
    u16x4 cb, pb, qb;
    #pragma unroll
    for (int j = 0; j < 4; ++j) {
      float c = ts[rr][c4 + i*4 + j];
      float p = tp[rr][c4 + i*4 + j] + lev[l * 256 + d0 + c4 + i*4 + j];
      cb[j] = f2b(c); pb[j] = f2b(p); qb[j] = f2b(c + p);
    }
    *(u16x4*)(cur_b + obase + c4 + i*4) = cb;
    *(u16x4*)(pos_b + obase + c4 + i*4) = pb;
    *(u16x4*)(q_b + obase + c4 + i*4) = qb;
  }
}

// ---------------------------------------------------------------------------
// Batched weight transpose+convert. Column-permuted placement: original
// output-column o stored at virtual row V(o)=((o&3)<<4)|(o>>2) within its
// 64-col group -> packed u16x4 epilogue stores.
__global__ __launch_bounds__(256) void wprep_kernel(
    const float* __restrict__ W_so, const float* __restrict__ W_aw,
    const float* __restrict__ W_v,  const float* __restrict__ W_o,
    const float* __restrict__ W_f1, const float* __restrict__ W_f2,
    ushort_t* __restrict__ wt)
{
  __shared__ float tile[64][65];
  int bx = blockIdx.x;
  int layer = bx / 184, r = bx % 184;
  int type, ti;
  if (r < 16)       { type = 0; ti = r; }
  else if (r < 24)  { type = 1; ti = r - 16; }
  else if (r < 40)  { type = 2; ti = r - 24; }
  else if (r < 56)  { type = 3; ti = r - 40; }
  else if (r < 120) { type = 4; ti = r - 56; }
  else              { type = 5; ti = r - 120; }
  const float* src;
  int K, N, dof;
  switch (type) {
    case 0: src = W_so + (size_t)layer * 65536;  K = 256;  N = 256;  dof = 0;      break;
    case 1: src = W_aw + (size_t)layer * 32768;  K = 256;  N = 128;  dof = 65536;  break;
    case 2: src = W_v  + (size_t)layer * 65536;  K = 256;  N = 256;  dof = 98304;  break;
    case 3: src = W_o  + (size_t)layer * 65536;  K = 256;  N = 256;  dof = 163840; break;
    case 4: src = W_f1 + (size_t)layer * 262144; K = 256;  N = 1024; dof = 229376; break;
    default:src = W_f2 + (size_t)layer * 262144; K = 1024; N = 256;  dof = 491520; break;
  }
  int Kt = K >> 6;
  int k0 = (ti % Kt) * 64, n0 = (ti / Kt) * 64;
  ushort_t* dst = wt + (size_t)layer * 753664 + dof;
  int t = threadIdx.x;
  int rr = t >> 2, c4 = (t & 3) * 16;
  #pragma unroll
  for (int i = 0; i < 4; ++i) {
    f32x4 v = *(const f32x4*)(src + (size_t)(k0 + rr) * N + n0 + c4 + i * 4);
    tile[c4 + i*4 + 0][rr] = v[0];
    tile[c4 + i*4 + 1][rr] = v[1];
    tile[c4 + i*4 + 2][rr] = v[2];
    tile[c4 + i*4 + 3][rr] = v[3];
  }
  __syncthreads();
  int vrow = ((rr & 3) << 4) | (rr >> 2);   // V(rr): epilogue-pack permutation
  #pragma unroll
  for (int i = 0; i < 4; ++i) {
    u16x4 o;
    #pragma unroll
    for (int j = 0; j < 4; ++j) o[j] = f2b(tile[rr][c4 + i*4 + j]);
    *(u16x4*)(dst + (size_t)(n0 + vrow) * K + k0 + c4 + i * 4) = o;
  }
}

__global__ void bias_fuse(const float* __restrict__ bso,
                          const float* __restrict__ baw,
                          float* __restrict__ bsa)
{
  int l = blockIdx.x, t = threadIdx.x;
  bsa[l * 384 + t] = (t < 256) ? bso[l * 256 + t] : baw[l * 128 + t - 256];
}

// ---------------------------------------------------------------------------
// 8-wave 256x128 MFMA GEMM body (BK=64, 512 threads, swizzled LDS).
__device__ __forceinline__ void gemm_body8(
    ushort_t* As, ushort_t* Bs,
    const ushort_t* __restrict__ A, const ushort_t* __restrict__ Bt,
    const float* __restrict__ bias, ushort_t* __restrict__ Cb,
    int N, int n0, int m0, int K, int relu)
{
  int t = threadIdx.x;
  int l = t & 63, w = t >> 6;
  int wr = w >> 1, wc = w & 1;
  int lq = l >> 4, l15 = l & 15, r7 = l & 7;
  f32x4 acc[4][4] = {};

  for (int k0 = 0; k0 < K; k0 += 64) {
    #pragma unroll
    for (int i = 0; i < 4; ++i) {
      int c = i * 512 + t;
      int row = c >> 3;
      int sc = (c & 7) ^ (row & 7);
      __builtin_amdgcn_global_load_lds(
          (const uint32_t*)(A + (size_t)(m0 + row) * K + k0 + sc * 8),
          (uint32_t*)((char*)As + c * 16), 16, 0, 0);
    }
    #pragma unroll
    for (int i = 0; i < 2; ++i) {
      int c = i * 512 + t;
      int row = c >> 3;
      int sc = (c & 7) ^ (row & 7);
      __builtin_amdgcn_global_load_lds(
          (const uint32_t*)(Bt + (size_t)(n0 + row) * K + k0 + sc * 8),
          (uint32_t*)((char*)Bs + c * 16), 16, 0, 0);
    }
    __syncthreads();
    #pragma unroll
    for (int ks = 0; ks < 2; ++ks) {
      bf16x8 af[4], bfr[4];
      int chs = ((ks << 2) + lq) ^ r7;
      #pragma unroll
      for (int mt = 0; mt < 4; ++mt)
        af[mt] = *(const bf16x8*)((const char*)As +
                   (wr * 64 + mt * 16 + l15) * 128 + (chs << 4));
      #pragma unroll
      for (int nt = 0; nt < 4; ++nt)
        bfr[nt] = *(const bf16x8*)((const char*)Bs +
                   (wc * 64 + nt * 16 + l15) * 128 + (chs << 4));
      #pragma unroll
      for (int mt = 0; mt < 4; ++mt)
        #pragma unroll
        for (int nt = 0; nt < 4; ++nt)
          acc[mt][nt] = __builtin_amdgcn_mfma_f32_16x16x32_bf16(
              af[mt], bfr[nt], acc[mt][nt], 0, 0, 0);
    }
    __syncthreads();
  }

  int crow0 = m0 + wr * 64;
  int cb = n0 + wc * 64 + l15 * 4;
  f32x4 bv4 = *(const f32x4*)(bias + cb);
  #pragma unroll
  for (int mt = 0; mt < 4; ++mt) {
    #pragma unroll
    for (int r = 0; r < 4; ++r) {
      int rowg = crow0 + mt * 16 + lq * 4 + r;
      u16x4 o;
      #pragma unroll
      for (int nt = 0; nt < 4; ++nt) {
        float v = acc[mt][nt][r] + bv4[nt];
        if (relu) v = fmaxf(v, 0.f);
        o[nt] = f2b(v);
      }
      *(u16x4*)(Cb + (size_t)rowg * N + cb) = o;
    }
  }
}

// FFN1 GEMM (relu), 256x128 tiles
__global__ __launch_bounds__(512) void gemm_mfma(
    const ushort_t* __restrict__ A, const ushort_t* __restrict__ Bt,
    const float* __restrict__ bias, ushort_t* __restrict__ Cb,
    int N, int K, int relu)
{
  __shared__ alignas(16) ushort_t As[16384];
  __shared__ alignas(16) ushort_t Bs[8192];
  gemm_body8(As, Bs, A, Bt, bias, Cb, N, blockIdx.y * 128, blockIdx.x * 256, K, relu);
}

// Merged sa(q@Wsa, N=384) + val(cur@Wv, N=256): grid (85, 5), 256-row tiles
__global__ __launch_bounds__(512) void gemm_dual(
    const ushort_t* __restrict__ A0, const ushort_t* __restrict__ Bt0,
    const float* __restrict__ bias0, ushort_t* __restrict__ C0,
    const ushort_t* __restrict__ A1, const ushort_t* __restrict__ Bt1,
    const float* __restrict__ bias1, ushort_t* __restrict__ C1,
    int K)
{
  __shared__ alignas(16) ushort_t As[16384];
  __shared__ alignas(16) ushort_t Bs[8192];
  int gy = blockIdx.y;
  if (gy < 3)
    gemm_body8(As, Bs, A0, Bt0, bias0, C0, 384, gy * 128, blockIdx.x * 256, K, 0);
  else
    gemm_body8(As, Bs, A1, Bt1, bias1, C1, 256, (gy - 3) * 128, blockIdx.x * 256, K, 0);
}

// ---------------------------------------------------------------------------
// Fused GEMM (N=256) + residual(bf16) + LayerNorm. Tile 64x256, 8 waves.
// Of (f32) written only when non-null (final layer).
__global__ __launch_bounds__(512) void gemm_ln(
    const ushort_t* __restrict__ A, const ushort_t* __restrict__ Bt,
    const float* __restrict__ bias, const ushort_t* __restrict__ resb,
    const float* __restrict__ g, const float* __restrict__ be,
    float* __restrict__ Of, ushort_t* __restrict__ Ob,
    ushort_t* __restrict__ Oq, const ushort_t* __restrict__ posb,
    int K)
{
  __shared__ alignas(16) ushort_t As[64 * 64];
  __shared__ alignas(16) ushort_t Bs[256 * 64];
  __shared__ float psum[64][4];
  __shared__ float psum2[64][4];
  __shared__ float2 mstd[64];
  int t = threadIdx.x;
  int l = t & 63, w = t >> 6;
  int wr = w >> 2, wc = w & 3;
  int m0 = blockIdx.x * 64;
  int lq = l >> 4, l15 = l & 15, r7 = l & 7;
  f32x4 acc[2][4] = {};

  for (int k0 = 0; k0 < K; k0 += 64) {
    {
      int c = t;
      int row = c >> 3;
      int sc = (c & 7) ^ (row & 7);
      __builtin_amdgcn_global_load_lds(
          (const uint32_t*)(A + (size_t)(m0 + row) * K + k0 + sc * 8),
          (uint32_t*)((char*)As + c * 16), 16, 0, 0);
    }
    #pragma unroll
    for (int i = 0; i < 4; ++i) {
      int c = i * 512 + t;
      int row = c >> 3;
      int sc = (c & 7) ^ (row & 7);
      __builtin_amdgcn_global_load_lds(
          (const uint32_t*)(Bt + (size_t)row * K + k0 + sc * 8),
          (uint32_t*)((char*)Bs + c * 16), 16, 0, 0);
    }
    __syncthreads();
    #pragma unroll
    for (int ks = 0; ks < 2; ++ks) {
      bf16x8 af[2], bfr[4];
      int chs = ((ks << 2) + lq) ^ r7;
      #pragma unroll
      for (int mt = 0; mt < 2; ++mt)
        af[mt] = *(const bf16x8*)((const char*)As +
                   (wr * 32 + mt * 16 + l15) * 128 + (chs << 4));
      #pragma unroll
      for (int nt = 0; nt < 4; ++nt)
        bfr[nt] = *(const bf16x8*)((const char*)Bs +
                   (wc * 64 + nt * 16 + l15) * 128 + (chs << 4));
      #pragma unroll
      for (int mt = 0; mt < 2; ++mt)
        #pragma unroll
        for (int nt = 0; nt < 4; ++nt)
          acc[mt][nt] = __builtin_amdgcn_mfma_f32_16x16x32_bf16(
              af[mt], bfr[nt], acc[mt][nt], 0, 0, 0);
    }
    __syncthreads();
  }

  int cb = wc * 64 + l15 * 4;
  f32x4 g4 = *(const f32x4*)(g + cb);
  f32x4 be4 = *(const f32x4*)(be + cb);
  f32x4 b4 = *(const f32x4*)(bias + cb);
  #pragma unroll
  for (int mt = 0; mt < 2; ++mt) {
    #pragma unroll
    for (int r = 0; r < 4; ++r) {
      int rowg = m0 + wr * 32 + mt * 16 + lq * 4 + r;
      u16x4 r4 = *(const u16x4*)(resb + (size_t)rowg * 256 + cb);
      #pragma unroll
      for (int nt = 0; nt < 4; ++nt)
        acc[mt][nt][r] += b4[nt] + b2f(r4[nt]);
    }
  }
  #pragma unroll
  for (int mt = 0; mt < 2; ++mt) {
    #pragma unroll
    for (int r = 0; r < 4; ++r) {
      float s = 0.f, s2 = 0.f;
      #pragma unroll
      for (int nt = 0; nt < 4; ++nt) {
        float v = acc[mt][nt][r];
        s += v; s2 += v * v;
      }
      #pragma unroll
      for (int off = 1; off < 16; off <<= 1) {
        s  += __shfl_xor(s, off);
        s2 += __shfl_xor(s2, off);
      }
      if (l15 == 0) {
        int rloc = wr * 32 + mt * 16 + lq * 4 + r;
        psum[rloc][wc] = s;
        psum2[rloc][wc] = s2;
      }
    }
  }
  __syncthreads();
  if (t < 64) {
    f32x4 a = *(const f32x4*)psum[t];
    f32x4 b = *(const f32x4*)psum2[t];
    float s = a[0] + a[1] + a[2] + a[3];
    float s2 = b[0] + b[1] + b[2] + b[3];
    float mean = s * (1.f / 256.f);
    float var = s2 * (1.f / 256.f) - mean * mean;
    mstd[t] = make_float2(mean, rsqrtf(var + 1e-5f));
  }
  __syncthreads();
  #pragma unroll
  for (int mt = 0; mt < 2; ++mt) {
    #pragma unroll
    for (int r = 0; r < 4; ++r) {
      int rloc = wr * 32 + mt * 16 + lq * 4 + r;
      int rowg = m0 + rloc;
      float2 ms = mstd[rloc];
      size_t o = (size_t)rowg * 256 + cb;
      f32x4 y4; u16x4 yb;
      #pragma unroll
      for (int nt = 0; nt < 4; ++nt) {
        float y = (acc[mt][nt][r] - ms.x) * ms.y * g4[nt] + be4[nt];
        y4[nt] = y; yb[nt] = f2b(y);
      }
      if (Of) *(f32x4*)(Of + o) = y4;
      *(u16x4*)(Ob + o) = yb;
      if (Oq) {
        u16x4 p4 = *(const u16x4*)(posb + o);
        u16x4 q4;
        #pragma unroll
        for (int nt = 0; nt < 4; ++nt) q4[nt] = f2b(y4[nt] + b2f(p4[nt]));
        *(u16x4*)(Oq + o) = q4;
      }
    }
  }
}

// ---------------------------------------------------------------------------
// Deformable sampling (best measured: v9): 8 tokens/block, 32 thr/token,
// XCD swizzle, 16B LDS records, 32-bit saddr offsets, k-unroll x2.
__global__ __launch_bounds__(256, 6) void sample_kernel(
    const ushort_t* __restrict__ val, const ushort_t* __restrict__ sa,
    ushort_t* __restrict__ att)
{
  __shared__ uint4 rec[8][136];
  int tid = threadIdx.x;
  int bid = blockIdx.x;
  int t0 = ((bid & 7) * 340 + (bid >> 3)) * 8;

  #pragma unroll
  for (int it = 0; it < 4; ++it) {
    int idx = it * 256 + tid;
    int tl = idx >> 7;
    int pt = idx & 127;
    int t = t0 + tl;
    int b = t / SSn, s = t % SSn;
    int lvl = (pt >> 2) & 3;
    int st, Wt;
    if (s < 4096)      { st = 0;    Wt = 64; }
    else if (s < 5120) { st = 4096; Wt = 32; }
    else if (s < 5376) { st = 5120; Wt = 16; }
    else               { st = 5376; Wt = 8;  }
    int p = s - st;
    int iy = p / Wt, ix = p % Wt;
    float refx = (ix + 0.5f) / Wt;
    float refy = (iy + 0.5f) / Wt;

    float logit = b2f(sa[(size_t)t * 384 + 256 + pt]);
    float m = logit;
    #pragma unroll
    for (int off = 1; off < 16; off <<= 1) m = fmaxf(m, __shfl_xor(m, off));
    float e = __expf(logit - m);
    float sum = e;
    #pragma unroll
    for (int off = 1; off < 16; off <<= 1) sum += __shfl_xor(sum, off);
    float wa = e / sum;

    const int LWt[4] = {64, 32, 16, 8};
    const int LST[4] = {0, 4096, 5120, 5376};
    int Wl = LWt[lvl], Hl = Wl, stl = LST[lvl];

    uint32_t oxy = *(const uint32_t*)(sa + (size_t)t * 384 + pt * 2);
    float ox = __uint_as_float(oxy << 16);
    float oy = __uint_as_float(oxy & 0xFFFF0000u);
    float x = refx * Wl + ox - 0.5f;
    float y = refy * Hl + oy - 0.5f;
    float x0f = floorf(x), y0f = floorf(y);
    int x0 = (int)x0f, y0 = (int)y0f;
    float wx1 = x - x0f, wy1 = y - y0f;
    int vbase = b * SSn + stl;
    uint32_t ipk[4]; uint32_t wpk[4];
    #pragma unroll
    for (int c = 0; c < 4; ++c) {
      int dx = c & 1, dy = c >> 1;
      int xi = x0 + dx, yi = y0 + dy;
      float wgt = (dx ? wx1 : 1.f - wx1) * (dy ? wy1 : 1.f - wy1);
      bool valid = (xi >= 0) & (xi < Wl) & (yi >= 0) & (yi < Hl);
      int xc = min(max(xi, 0), Wl - 1), yc = min(max(yi, 0), Hl - 1);
      ipk[c] = (uint32_t)(vbase + yc * Wl + xc);
      wpk[c] = valid ? (uint32_t)f2b(wgt * wa) : 0u;
    }
    uint4 r;
    r.x = ipk[0] | (ipk[1] << 16);
    r.y = ipk[2] | (ipk[3] << 16);
    r.z = wpk[0] | (wpk[1] << 16);
    r.w = wpk[2] | (wpk[3] << 16);
    rec[tl][pt + (pt >> 4)] = r;
  }
  __syncthreads();

  int tl = tid >> 5, v = tid & 31;
  int t = t0 + tl;
  int h = v >> 2, j = v & 3;
  int c0 = h * 32 + j * 8;
  uint32_t cb2 = (uint32_t)(c0 * 2);
  const char* vb = (const char*)val;
  f32x2 acA[4] = {}, acB[4] = {};
  #pragma unroll
  for (int k = 0; k < 16; k += 2) {
    uint4 rA = rec[tl][h * 17 + k];
    uint4 rB = rec[tl][h * 17 + k + 1];
    uint32_t oA0 = ((rA.x & 0xFFFFu) << 9) + cb2;
    uint32_t oA1 = ((rA.x >> 16)     << 9) + cb2;
    uint32_t oA2 = ((rA.y & 0xFFFFu) << 9) + cb2;
    uint32_t oA3 = ((rA.y >> 16)     << 9) + cb2;
    uint32_t oB0 = ((rB.x & 0xFFFFu) << 9) + cb2;
    uint32_t oB1 = ((rB.x >> 16)     << 9) + cb2;
    uint32_t oB2 = ((rB.y & 0xFFFFu) << 9) + cb2;
    uint32_t oB3 = ((rB.y >> 16)     << 9) + cb2;
    uint4 uA0 = *(const uint4*)(vb + oA0);
    uint4 uA1 = *(const uint4*)(vb + oA1);
    uint4 uA2 = *(const uint4*)(vb + oA2);
    uint4 uA3 = *(const uint4*)(vb + oA3);
    uint4 uB0 = *(const uint4*)(vb + oB0);
    uint4 uB1 = *(const uint4*)(vb + oB1);
    uint4 uB2 = *(const uint4*)(vb + oB2);
    uint4 uB3 = *(const uint4*)(vb + oB3);
    float wA[4] = { __uint_as_float(rA.z << 16),
                    __uint_as_float(rA.z & 0xFFFF0000u),
                    __uint_as_float(rA.w << 16),
                    __uint_as_float(rA.w & 0xFFFF0000u) };
    float wB[4] = { __uint_as_float(rB.z << 16),
                    __uint_as_float(rB.z & 0xFFFF0000u),
                    __uint_as_float(rB.w << 16),
                    __uint_as_float(rB.w & 0xFFFF0000u) };
    const uint4* uvA[4] = { &uA0, &uA1, &uA2, &uA3 };
    const uint4* uvB[4] = { &uB0, &uB1, &uB2, &uB3 };
    #pragma unroll
    for (int c = 0; c < 4; ++c) {
      uint4 uv = *uvA[c];
      f32x2 w2 = {wA[c], wA[c]};
      f32x2 p0 = {__uint_as_float(uv.x << 16), __uint_as_float(uv.x & 0xFFFF0000u)};
      f32x2 p1 = {__uint_as_float(uv.y << 16), __uint_as_float(uv.y & 0xFFFF0000u)};
      f32x2 p2 = {__uint_as_float(uv.z << 16), __uint_as_float(uv.z & 0xFFFF0000u)};
      f32x2 p3 = {__uint_as_float(uv.w << 16), __uint_as_float(uv.w & 0xFFFF0000u)};
      acA[0] += w2 * p0; acA[1] += w2 * p1; acA[2] += w2 * p2; acA[3] += w2 * p3;
    }
    #pragma unroll
    for (int c = 0; c < 4; ++c) {
      uint4 uv = *uvB[c];
      f32x2 w2 = {wB[c], wB[c]};
      f32x2 p0 = {__uint_as_float(uv.x << 16), __uint_as_float(uv.x & 0xFFFF0000u)};
      f32x2 p1 = {__uint_as_float(uv.y << 16), __uint_as_float(uv.y & 0xFFFF0000u)};
      f32x2 p2 = {__uint_as_float(uv.z << 16), __uint_as_float(uv.z & 0xFFFF0000u)};
      f32x2 p3 = {__uint_as_float(uv.w << 16), __uint_as_float(uv.w & 0xFFFF0000u)};
      acB[0] += w2 * p0; acB[1] += w2 * p1; acB[2] += w2 * p2; acB[3] += w2 * p3;
    }
  }
  #pragma unroll
  for (int i = 0; i < 4; ++i) acA[i] += acB[i];
  uint4 pk;
  pk.x = (uint32_t)f2b(acA[0][0]) | ((uint32_t)f2b(acA[0][1]) << 16);
  pk.y = (uint32_t)f2b(acA[1][0]) | ((uint32_t)f2b(acA[1][1]) << 16);
  pk.z = (uint32_t)f2b(acA[2][0]) | ((uint32_t)f2b(acA[2][1]) << 16);
  pk.w = (uint32_t)f2b(acA[3][0]) | ((uint32_t)f2b(acA[3][1]) << 16);
  *(uint4*)(att + (size_t)t * 256 + c0) = pk;
}

// ---------------------------------------------------------------------------
__global__ void tail_kernel(float* __restrict__ o) {
  const float v[12] = {64.f, 64.f, 32.f, 32.f, 16.f, 16.f, 8.f, 8.f,
                       0.f, 4096.f, 5120.f, 5376.f};
  int i = threadIdx.x;
  if (i < 12) o[i] = v[i];
}

// ---------------------------------------------------------------------------
extern "C" void kernel_launch(void* const* d_in, const int* in_sizes, int n_in,
                              void* d_out, int out_size, void* d_ws, size_t ws_size,
                              hipStream_t stream)
{
  const float* s0  = (const float*)d_in[0];
  const float* p0  = (const float*)d_in[1];
  const float* s1  = (const float*)d_in[2];
  const float* p1  = (const float*)d_in[3];
  const float* s2  = (const float*)d_in[4];
  const float* p2  = (const float*)d_in[5];
  const float* s3  = (const float*)d_in[6];
  const float* p3  = (const float*)d_in[7];
  const float* lev = (const float*)d_in[8];
  const float* W_so = (const float*)d_in[9];
  const float* b_so = (const float*)d_in[10];
  const float* W_aw = (const float*)d_in[11];
  const float* b_aw = (const float*)d_in[12];
  const float* W_v  = (const float*)d_in[13];
  const float* b_v  = (const float*)d_in[14];
  const float* W_o  = (const float*)d_in[15];
  const float* b_o  = (const float*)d_in[16];
  const float* g1   = (const float*)d_in[17];
  const float* be1  = (const float*)d_in[18];
  const float* W_f1 = (const float*)d_in[19];
  const float* b_f1 = (const float*)d_in[20];
  const float* W_f2 = (const float*)d_in[21];
  const float* b_f2 = (const float*)d_in[22];
  const float* g2   = (const float*)d_in[23];
  const float* be2  = (const float*)d_in[24];

  float* out = (float*)d_out;
  float* ws  = (float*)d_ws;

  // workspace layout (f32 units)
  ushort_t* pos_b = (ushort_t*)ws;                          // 0.5 TD
  ushort_t* q_b   = (ushort_t*)(ws + TD / 2);               // 0.5 TD (q / att)
  ushort_t* cur_b = (ushort_t*)(ws + TD);                   // 0.5 TD
  ushort_t* x_b   = (ushort_t*)(ws + TD + TD / 2);          // 0.5 TD
  // H region: phase1 sa_b (0.75 TD) + val_b (0.5 TD); phase3 h_b (2 TD)
  ushort_t* sa_b  = (ushort_t*)(ws + 2 * TD);
  ushort_t* val_b = (ushort_t*)(ws + 2 * TD + 3 * (TD / 4));
  ushort_t* h_b   = (ushort_t*)(ws + 2 * TD);
  ushort_t* wt    = (ushort_t*)(ws + 4 * TD);               // 4,521,984 bf16
  float*    bsa   = ws + 4 * TD + 2260992;                  // 6*384 f32

  const size_t LW = 753664;  // per-layer transposed-weight stride (bf16)

  wprep_kernel<<<1104, 256, 0, stream>>>(W_so, W_aw, W_v, W_o, W_f1, W_f2, wt);
  bias_fuse<<<NL, 384, 0, stream>>>(b_so, b_aw, bsa);
  prep_kernel<<<1360, 256, 0, stream>>>(s0, p0, s1, p1, s2, p2, s3, p3, lev,
                                        cur_b, pos_b, q_b);

  for (int i = 0; i < NL; ++i) {
    ushort_t* wl = wt + (size_t)i * LW;
    const float* bv  = b_v  + (size_t)i * 256;
    const float* bo  = b_o  + (size_t)i * 256;
    const float* bf1 = b_f1 + (size_t)i * 1024;
    const float* bf2 = b_f2 + (size_t)i * 256;

    // merged: sa = q@Wsa (N=384) and val = cur@Wv (N=256), 256-row tiles
    gemm_dual<<<dim3(85, 5), 512, 0, stream>>>(q_b, wl + 0, bsa + i * 384, sa_b,
                                               cur_b, wl + 98304, bv, val_b, 256);
    // deformable sampling -> att (bf16, overwrites q_b)
    sample_kernel<<<TTn / 8, 256, 0, stream>>>(val_b, sa_b, q_b);
    // Wo projection + residual(cur_b) + LN1 -> x_b (bf16 only)
    gemm_ln<<<340, 512, 0, stream>>>(q_b, wl + 163840, bo, cur_b,
                                     g1 + i * 256, be1 + i * 256,
                                     nullptr, x_b, nullptr, nullptr, 256);
    // FFN1 (relu) -> h_b, 256x128 tiles
    gemm_mfma<<<dim3(85, 8), 512, 0, stream>>>(x_b, wl + 229376, bf1,
                                               h_b, 1024, 256, 1);
    // FFN2 + residual(x_b) + LN2 -> cur_b, q_b(next = y+pos); f32 out on last
    gemm_ln<<<340, 512, 0, stream>>>(h_b, wl + 491520, bf2, x_b,
                                     g2 + i * 256, be2 + i * 256,
                                     (i == NL - 1) ? out : nullptr,
                                     cur_b, q_b, pos_b, 1024);
  }

  tail_kernel<<<1, 16, 0, stream>>>(out + TD);
}